// Round 3
// baseline (196.743 us; speedup 1.0000x reference)
//
#include <hip/hip_runtime.h>

typedef __attribute__((ext_vector_type(8))) short bf16x8;
typedef __attribute__((ext_vector_type(4))) float f32x4;
typedef __attribute__((ext_vector_type(4))) unsigned short u16x4;
typedef __attribute__((ext_vector_type(8))) unsigned short u16x8;

__device__ __forceinline__ ushort f2bf(float f) {
    unsigned u = __float_as_uint(f);
    unsigned r = (u + 0x7FFFu + ((u >> 16) & 1u)) >> 16;
    return (ushort)r;
}
__device__ __forceinline__ float bf2f(ushort s) {
    return __uint_as_float(((unsigned)s) << 16);
}

// async global->LDS, 16B per lane. LDS dest is wave-uniform base + lane*16.
__device__ __forceinline__ void async16(const ushort* g, ushort* l) {
    __builtin_amdgcn_global_load_lds(
        (const __attribute__((address_space(1))) unsigned*)g,
        (__attribute__((address_space(3))) unsigned*)l, 16, 0, 0);
}

// ---------------------------------------------------------------------------
// Kernel 0a: straight fp32 -> bf16 conversion of x (8192x1024) and Wv (1024x1024).
// ---------------------------------------------------------------------------
__global__ __launch_bounds__(256) void cvt_bf16(
    const float* __restrict__ x, const float* __restrict__ wv,
    ushort* __restrict__ xb, ushort* __restrict__ wvb)
{
    const size_t XN = (size_t)8192 * 1024;
    size_t idx = ((size_t)blockIdx.x * 256 + threadIdx.x) * 8;
    const float* s;
    ushort* d;
    if (idx < XN) { s = x + idx; d = xb + idx; }
    else          { s = wv + (idx - XN); d = wvb + (idx - XN); }
    float4 a = *(const float4*)s;
    float4 b = *(const float4*)(s + 4);
    u16x8 p;
    p[0] = f2bf(a.x); p[1] = f2bf(a.y); p[2] = f2bf(a.z); p[3] = f2bf(a.w);
    p[4] = f2bf(b.x); p[5] = f2bf(b.y); p[6] = f2bf(b.z); p[7] = f2bf(b.w);
    *(u16x8*)d = p;
}

// ---------------------------------------------------------------------------
// Kernel 0b: transposing fp32 -> bf16 for Wk and Wq: out[d][e] = in[e][d].
// block (32,8), grid (32,32,2).
// ---------------------------------------------------------------------------
__global__ __launch_bounds__(256) void cvt_transpose(
    const float* __restrict__ w0, const float* __restrict__ w1,
    ushort* __restrict__ t0, ushort* __restrict__ t1)
{
    const float* src = blockIdx.z ? w1 : w0;
    ushort*      dst = blockIdx.z ? t1 : t0;
    __shared__ float t[32][33];
    const int e0 = blockIdx.x * 32, d0 = blockIdx.y * 32;
    const int tx = threadIdx.x, ty = threadIdx.y;
#pragma unroll
    for (int r = 0; r < 4; ++r)
        t[ty + 8 * r][tx] = src[(size_t)(e0 + ty + 8 * r) * 1024 + d0 + tx];
    __syncthreads();
#pragma unroll
    for (int r = 0; r < 4; ++r)
        dst[(size_t)(d0 + ty + 8 * r) * 1024 + e0 + tx] = f2bf(t[tx][ty + 8 * r]);
}

// ---------------------------------------------------------------------------
// Shared m97-style GEMM core: 128x128 tile, BK=64, 4 waves (2x2 of 64x64),
// global_load_lds dwordx4 staging, mfma_f32_16x16x32_bf16.
// A, B row-major [rows][K] (B in "B^T" N x K layout).
// ---------------------------------------------------------------------------
__device__ __forceinline__ void mma_tile(
    const ushort* __restrict__ A, int lda, int abase,
    const ushort* __restrict__ B, int ldb, int bbase,
    int ktiles,
    ushort* As, ushort* Bs, f32x4 (&acc)[4][4])
{
    const int tid  = threadIdx.x;
    const int lane = tid & 63, wid = tid >> 6;
    const int wr = wid >> 1, wc = wid & 1;
    const int lrow = lane & 15, kgrp = lane >> 4;
    const int ci = lane >> 3;          // row within 8-row group
    const int cc = (lane & 7) * 8;     // col (bf16 elems)

#pragma unroll
    for (int m = 0; m < 4; ++m)
#pragma unroll
        for (int n = 0; n < 4; ++n) acc[m][n] = (f32x4){0.f, 0.f, 0.f, 0.f};

    for (int kt = 0; kt < ktiles; ++kt) {
        const int k0 = kt * 64;
#pragma unroll
        for (int i = 0; i < 4; ++i) {
            const int r = (wid * 4 + i) * 8 + ci;
            async16(&A[(size_t)(abase + r) * lda + k0 + cc], &As[(wid * 4 + i) * 512]);
            async16(&B[(size_t)(bbase + r) * ldb + k0 + cc], &Bs[(wid * 4 + i) * 512]);
        }
        __syncthreads();
#pragma unroll
        for (int kk = 0; kk < 2; ++kk) {
            bf16x8 af[4], bfr[4];
#pragma unroll
            for (int m = 0; m < 4; ++m)
                af[m] = *(const bf16x8*)&As[(wr * 64 + m * 16 + lrow) * 64 + kk * 32 + kgrp * 8];
#pragma unroll
            for (int n = 0; n < 4; ++n)
                bfr[n] = *(const bf16x8*)&Bs[(wc * 64 + n * 16 + lrow) * 64 + kk * 32 + kgrp * 8];
#pragma unroll
            for (int m = 0; m < 4; ++m)
#pragma unroll
                for (int n = 0; n < 4; ++n)
                    acc[m][n] = __builtin_amdgcn_mfma_f32_16x16x32_bf16(af[m], bfr[n], acc[m][n], 0, 0, 0);
        }
        __syncthreads();
    }
}

// ---------------------------------------------------------------------------
// Kernel 1: Mtr[f][d] = sum_e Wkt[f][e] * Wqt[d][e]  ( = (Wq^T Wk)[d][f] ).
// Output bf16 [1024][1024], which is exactly the NxK operand for T = x @ M.
// ---------------------------------------------------------------------------
__global__ __launch_bounds__(256) void m_gemm(
    const ushort* __restrict__ Wkt, const ushort* __restrict__ Wqt,
    ushort* __restrict__ Mtr)
{
    __shared__ ushort As[128 * 64];
    __shared__ ushort Bs[128 * 64];
    const int fbase = blockIdx.x * 128;
    const int dbase = blockIdx.y * 128;

    f32x4 acc[4][4];
    mma_tile(Wkt, 1024, fbase, Wqt, 1024, dbase, 16, As, Bs, acc);

    const int lane = threadIdx.x & 63, wid = threadIdx.x >> 6;
    const int wr = wid >> 1, wc = wid & 1;
    const int lrow = lane & 15, kgrp = lane >> 4;
#pragma unroll
    for (int m = 0; m < 4; ++m)
#pragma unroll
        for (int n = 0; n < 4; ++n)
#pragma unroll
            for (int r = 0; r < 4; ++r) {
                const int gf = fbase + wr * 64 + m * 16 + kgrp * 4 + r;
                const int gd = dbase + wc * 64 + n * 16 + lrow;
                Mtr[(size_t)gf * 1024 + gd] = f2bf(acc[m][n][r]);
            }
}

// ---------------------------------------------------------------------------
// Kernel 2: z=0: T = xb @ Mtr^T(NxK) -> Tb row-major [8192][1024] bf16.
//           z=1: V = xb @ Wvb^T     -> Vt transposed per batch [1024][2048].
// ---------------------------------------------------------------------------
__global__ __launch_bounds__(256) void tv_gemm(
    const ushort* __restrict__ xb, const ushort* __restrict__ Mtr,
    const ushort* __restrict__ Wvb,
    ushort* __restrict__ Tb, ushort* __restrict__ Vt)
{
    __shared__ ushort As[128 * 64];
    __shared__ ushort Bs[128 * 64];

    const int z = blockIdx.z;
    const ushort* B = z ? Wvb : Mtr;
    const int mbase = blockIdx.x * 128;
    const int nbase = blockIdx.y * 128;

    f32x4 acc[4][4];
    mma_tile(xb, 1024, mbase, B, 1024, nbase, 16, As, Bs, acc);

    const int lane = threadIdx.x & 63, wid = threadIdx.x >> 6;
    const int wr = wid >> 1, wc = wid & 1;
    const int lrow = lane & 15, kgrp = lane >> 4;

    if (z == 1) {
        // write V transposed: Vt[batch][d][s], 4 consecutive s per 8B store
        const int b  = mbase >> 11;
        const int s0 = mbase & 2047;
        ushort* VtB = Vt + (size_t)b * 1024 * 2048;
#pragma unroll
        for (int m = 0; m < 4; ++m)
#pragma unroll
            for (int n = 0; n < 4; ++n) {
                u16x4 pk;
#pragma unroll
                for (int r = 0; r < 4; ++r) pk[r] = f2bf(acc[m][n][r]);
                const int d = nbase + wc * 64 + n * 16 + lrow;
                const int s = s0 + wr * 64 + m * 16 + kgrp * 4;
                *(u16x4*)&VtB[(size_t)d * 2048 + s] = pk;
            }
    } else {
#pragma unroll
        for (int m = 0; m < 4; ++m)
#pragma unroll
            for (int n = 0; n < 4; ++n)
#pragma unroll
                for (int r = 0; r < 4; ++r) {
                    const int gr = mbase + wr * 64 + m * 16 + kgrp * 4 + r;
                    const int gc = nbase + wc * 64 + n * 16 + lrow;
                    Tb[(size_t)gr * 1024 + gc] = f2bf(acc[m][n][r]);
                }
    }
}

// ---------------------------------------------------------------------------
// Kernel 3: scores S = (T @ x^T) / 32, lower-triangular 128x128 tiles only.
// A = Tb rows, B = xb rows (both [batch*2048 + s][1024]).
// ---------------------------------------------------------------------------
__global__ __launch_bounds__(256) void scores_gemm(
    const ushort* __restrict__ Tb, const ushort* __restrict__ xb,
    ushort* __restrict__ Sall)
{
    __shared__ ushort As[128 * 64];
    __shared__ ushort Bs[128 * 64];

    ushort* S = Sall + (size_t)blockIdx.y * 2048 * 2048;
    const int rb = blockIdx.y * 2048;

    int t = blockIdx.x;
    int it = (int)((sqrtf(8.0f * (float)t + 1.0f) - 1.0f) * 0.5f);
    while ((it + 1) * (it + 2) / 2 <= t) ++it;
    while (it * (it + 1) / 2 > t) --it;
    const int jt = t - it * (it + 1) / 2;
    const int ibase = it * 128, jbase = jt * 128;

    f32x4 acc[4][4];
    mma_tile(Tb, 1024, rb + ibase, xb, 1024, rb + jbase, 16, As, Bs, acc);

    const int lane = threadIdx.x & 63, wid = threadIdx.x >> 6;
    const int wr = wid >> 1, wc = wid & 1;
    const int lrow = lane & 15, kgrp = lane >> 4;
#pragma unroll
    for (int m = 0; m < 4; ++m)
#pragma unroll
        for (int n = 0; n < 4; ++n)
#pragma unroll
            for (int r = 0; r < 4; ++r) {
                const int gi = ibase + wr * 64 + m * 16 + kgrp * 4 + r;
                const int gj = jbase + wc * 64 + n * 16 + lrow;
                S[(size_t)gi * 2048 + gj] = f2bf(acc[m][n][r] * 0.03125f);
            }
}

// ---------------------------------------------------------------------------
// Kernel 4: causal row softmax in place on bf16 S. One block per row.
// Skips loads for fully-masked chunks; writes zeros there (PV reads dense).
// ---------------------------------------------------------------------------
__global__ __launch_bounds__(256) void softmax_rows(ushort* __restrict__ Sall)
{
    ushort* S = Sall + (size_t)blockIdx.y * 2048 * 2048;
    const int i   = blockIdx.x;
    const int tid = threadIdx.x;
    const int j0  = tid * 8;

    union { uint4 v; ushort u[8]; } pk;
    const bool anyvalid = (j0 <= i);
    if (anyvalid) pk.v = *(const uint4*)&S[(size_t)i * 2048 + j0];

    float f[8];
    float mx = -INFINITY;
#pragma unroll
    for (int e = 0; e < 8; ++e) {
        float v = (anyvalid && (j0 + e <= i)) ? bf2f(pk.u[e]) : -INFINITY;
        f[e] = v;
        mx = fmaxf(mx, v);
    }
#pragma unroll
    for (int off = 1; off < 64; off <<= 1) mx = fmaxf(mx, __shfl_xor(mx, off));
    __shared__ float redm[4];
    if ((tid & 63) == 0) redm[tid >> 6] = mx;
    __syncthreads();
    mx = fmaxf(fmaxf(redm[0], redm[1]), fmaxf(redm[2], redm[3]));

    float s = 0.f;
#pragma unroll
    for (int e = 0; e < 8; ++e) {
        float p = __expf(f[e] - mx);
        f[e] = p;
        s += p;
    }
#pragma unroll
    for (int off = 1; off < 64; off <<= 1) s += __shfl_xor(s, off);
    __shared__ float reds[4];
    if ((tid & 63) == 0) reds[tid >> 6] = s;
    __syncthreads();
    s = reds[0] + reds[1] + reds[2] + reds[3];

    const float inv = 1.0f / s;
#pragma unroll
    for (int e = 0; e < 8; ++e) pk.u[e] = f2bf(f[e] * inv);
    *(uint4*)&S[(size_t)i * 2048 + j0] = pk.v;
}

// ---------------------------------------------------------------------------
// Kernel 5: O = P @ V. P bf16 [2048][2048] (upper triangle zeroed),
// Vt bf16 [1024][2048] per batch. K-loop truncated at diagonal. fp32 out.
// Heaviest row-tiles dispatched first (it = 15 - bx).
// ---------------------------------------------------------------------------
__global__ __launch_bounds__(256) void pv_gemm(
    const ushort* __restrict__ Pall, const ushort* __restrict__ Vtall,
    float* __restrict__ Oall)
{
    __shared__ ushort As[128 * 64];
    __shared__ ushort Bs[128 * 64];

    const ushort* P  = Pall  + (size_t)blockIdx.z * 2048 * 2048;
    const ushort* Vt = Vtall + (size_t)blockIdx.z * 1024 * 2048;
    float*        O  = Oall  + (size_t)blockIdx.z * 2048 * 1024;

    const int it = 15 - blockIdx.x;
    const int ibase = it * 128;
    const int nbase = blockIdx.y * 128;
    const int ktiles = 2 * (it + 1);

    f32x4 acc[4][4];
    mma_tile(P, 2048, ibase, Vt, 2048, nbase, ktiles, As, Bs, acc);

    const int lane = threadIdx.x & 63, wid = threadIdx.x >> 6;
    const int wr = wid >> 1, wc = wid & 1;
    const int lrow = lane & 15, kgrp = lane >> 4;
#pragma unroll
    for (int m = 0; m < 4; ++m)
#pragma unroll
        for (int n = 0; n < 4; ++n)
#pragma unroll
            for (int r = 0; r < 4; ++r) {
                const int gi = ibase + wr * 64 + m * 16 + kgrp * 4 + r;
                const int gc = nbase + wc * 64 + n * 16 + lrow;
                O[(size_t)gi * 1024 + gc] = acc[m][n][r];
            }
}

// ---------------------------------------------------------------------------
extern "C" void kernel_launch(void* const* d_in, const int* in_sizes, int n_in,
                              void* d_out, int out_size, void* d_ws, size_t ws_size,
                              hipStream_t stream)
{
    (void)in_sizes; (void)n_in; (void)out_size; (void)ws_size;
    const float* x  = (const float*)d_in[0];
    const float* Wk = (const float*)d_in[1];
    const float* Wq = (const float*)d_in[2];
    const float* Wv = (const float*)d_in[3];
    float* out = (float*)d_out;

    const size_t M1 = (size_t)1024 * 1024;
    ushort* ws  = (ushort*)d_ws;
    ushort* xb  = ws;                      // 8M elems
    ushort* Tb  = xb  + 8 * M1;            // 8M
    ushort* Vt  = Tb  + 8 * M1;            // 8M (4 x [1024][2048])
    ushort* Sb  = Vt  + 8 * M1;            // 16M (4 x [2048][2048])
    ushort* Wkt = Sb  + 16 * M1;           // 1M
    ushort* Wqt = Wkt + M1;                // 1M
    ushort* Wvb = Wqt + M1;                // 1M
    ushort* Mtr = Wvb + M1;                // 1M   => total 44M elems = 88 MB

    // 0b) transpose-convert Wk, Wq
    cvt_transpose<<<dim3(32, 32, 2), dim3(32, 8), 0, stream>>>(Wk, Wq, Wkt, Wqt);
    // 1) M = (Wq^T Wk) stored transposed (NxK operand for T)
    m_gemm<<<dim3(8, 8), 256, 0, stream>>>(Wkt, Wqt, Mtr);
    // 0a) straight-convert x, Wv
    cvt_bf16<<<4608, 256, 0, stream>>>(x, Wv, xb, Wvb);
    // 2) T = x@M (z=0), V^T (z=1); grid = 1024 blocks = 4/CU exactly
    tv_gemm<<<dim3(64, 8, 2), 256, 0, stream>>>(xb, Mtr, Wvb, Tb, Vt);
    // 3) scores, lower-triangular tiles
    scores_gemm<<<dim3(136, 4), 256, 0, stream>>>(Tb, xb, Sb);
    // 4) softmax in place
    softmax_rows<<<dim3(2048, 4), 256, 0, stream>>>(Sb);
    // 5) O = P @ V
    pv_gemm<<<dim3(16, 8, 4), 256, 0, stream>>>(Sb, Vt, out);
}

// Round 4
// 177.027 us; speedup vs baseline: 1.1114x; 1.1114x over previous
//
#include <hip/hip_runtime.h>

typedef __attribute__((ext_vector_type(8))) short bf16x8;
typedef __attribute__((ext_vector_type(4))) float f32x4;
typedef __attribute__((ext_vector_type(4))) unsigned short u16x4;
typedef __attribute__((ext_vector_type(8))) unsigned short u16x8;

#define MFMA16(a, b, c) __builtin_amdgcn_mfma_f32_16x16x32_bf16((a), (b), (c), 0, 0, 0)

__device__ __forceinline__ ushort f2bf(float f) {
    unsigned u = __float_as_uint(f);
    unsigned r = (u + 0x7FFFu + ((u >> 16) & 1u)) >> 16;
    return (ushort)r;
}
__device__ __forceinline__ float bf2f(ushort s) {
    return __uint_as_float(((unsigned)s) << 16);
}

// async global->LDS, 16B per lane. LDS dest is wave-uniform base + lane*16.
__device__ __forceinline__ void async16(const ushort* g, ushort* l) {
    __builtin_amdgcn_global_load_lds(
        (const __attribute__((address_space(1))) unsigned*)g,
        (__attribute__((address_space(3))) unsigned*)l, 16, 0, 0);
}

#define SBAR()  __builtin_amdgcn_s_barrier()
#define SCHED() __builtin_amdgcn_sched_barrier(0)

// ---------------------------------------------------------------------------
// Kernel 0a: straight fp32 -> bf16 conversion of x (8192x1024) and Wv (1024x1024).
// ---------------------------------------------------------------------------
__global__ __launch_bounds__(256) void cvt_bf16(
    const float* __restrict__ x, const float* __restrict__ wv,
    ushort* __restrict__ xb, ushort* __restrict__ wvb)
{
    const size_t XN = (size_t)8192 * 1024;
    size_t idx = ((size_t)blockIdx.x * 256 + threadIdx.x) * 8;
    const float* s;
    ushort* d;
    if (idx < XN) { s = x + idx; d = xb + idx; }
    else          { s = wv + (idx - XN); d = wvb + (idx - XN); }
    float4 a = *(const float4*)s;
    float4 b = *(const float4*)(s + 4);
    u16x8 p;
    p[0] = f2bf(a.x); p[1] = f2bf(a.y); p[2] = f2bf(a.z); p[3] = f2bf(a.w);
    p[4] = f2bf(b.x); p[5] = f2bf(b.y); p[6] = f2bf(b.z); p[7] = f2bf(b.w);
    *(u16x8*)d = p;
}

// ---------------------------------------------------------------------------
// Kernel 0b: transposing fp32 -> bf16 for Wk and Wq: out[d][e] = in[e][d].
// ---------------------------------------------------------------------------
__global__ __launch_bounds__(256) void cvt_transpose(
    const float* __restrict__ w0, const float* __restrict__ w1,
    ushort* __restrict__ t0, ushort* __restrict__ t1)
{
    const float* src = blockIdx.z ? w1 : w0;
    ushort*      dst = blockIdx.z ? t1 : t0;
    __shared__ float t[32][33];
    const int e0 = blockIdx.x * 32, d0 = blockIdx.y * 32;
    const int tx = threadIdx.x, ty = threadIdx.y;
#pragma unroll
    for (int r = 0; r < 4; ++r)
        t[ty + 8 * r][tx] = src[(size_t)(e0 + ty + 8 * r) * 1024 + d0 + tx];
    __syncthreads();
#pragma unroll
    for (int r = 0; r < 4; ++r)
        dst[(size_t)(d0 + ty + 8 * r) * 1024 + e0 + tx] = f2bf(t[tx][ty + 8 * r]);
}

// ---------------------------------------------------------------------------
// 2-phase 128x128 core (kept for m_gemm / pv_gemm). 256 threads.
// ---------------------------------------------------------------------------
__device__ __forceinline__ void mma_tile(
    const ushort* __restrict__ A, int lda, int abase,
    const ushort* __restrict__ B, int ldb, int bbase,
    int ktiles,
    ushort* As, ushort* Bs, f32x4 (&acc)[4][4])
{
    const int tid  = threadIdx.x;
    const int lane = tid & 63, wid = tid >> 6;
    const int wr = wid >> 1, wc = wid & 1;
    const int lrow = lane & 15, kgrp = lane >> 4;
    const int ci = lane >> 3;
    const int cc = (lane & 7) * 8;

#pragma unroll
    for (int m = 0; m < 4; ++m)
#pragma unroll
        for (int n = 0; n < 4; ++n) acc[m][n] = (f32x4){0.f, 0.f, 0.f, 0.f};

    for (int kt = 0; kt < ktiles; ++kt) {
        const int k0 = kt * 64;
#pragma unroll
        for (int i = 0; i < 4; ++i) {
            const int r = (wid * 4 + i) * 8 + ci;
            async16(&A[(size_t)(abase + r) * lda + k0 + cc], &As[(wid * 4 + i) * 512]);
            async16(&B[(size_t)(bbase + r) * ldb + k0 + cc], &Bs[(wid * 4 + i) * 512]);
        }
        __syncthreads();
#pragma unroll
        for (int kk = 0; kk < 2; ++kk) {
            bf16x8 af[4], bfr[4];
#pragma unroll
            for (int m = 0; m < 4; ++m)
                af[m] = *(const bf16x8*)&As[(wr * 64 + m * 16 + lrow) * 64 + kk * 32 + kgrp * 8];
#pragma unroll
            for (int n = 0; n < 4; ++n)
                bfr[n] = *(const bf16x8*)&Bs[(wc * 64 + n * 16 + lrow) * 64 + kk * 32 + kgrp * 8];
#pragma unroll
            for (int m = 0; m < 4; ++m)
#pragma unroll
                for (int n = 0; n < 4; ++n)
                    acc[m][n] = MFMA16(af[m], bfr[n], acc[m][n]);
        }
        __syncthreads();
    }
}

// ---------------------------------------------------------------------------
// 8-phase 256x256 core. 512 threads = 8 waves (2 Mrows x 4 Ncols).
// LDS: As/Bs each [2 buf][2 kk-half][256 rows][32 k] bf16 (64 KiB each).
// Halves per K-tile: {A,B} x {k0,k1}; 2 global_load_lds per thread per half.
// Phase quadrants: (kk0,n01)(kk0,n23)(kk1,n01)(kk1,n23).
// Stage map: P1:(t+1,A,k1) P2:(t+1,B,k1) P3:(t+2,A,k0) P4:(t+2,B,k0).
// One vmcnt(4) per K-tile at P4 -> all 4 halves of t+1 complete before t+1.P1.
// Ledger: every staged slot is >=2 barriers dead at issue; every consumed slot
// is vmcnt-guarded >=2 barriers before first ds_read.
// ---------------------------------------------------------------------------
__device__ __forceinline__ void mma256(
    const ushort* __restrict__ A, int lda, int abase,
    const ushort* __restrict__ B, int ldb, int bbase,
    int NT, ushort* As, ushort* Bs, f32x4 (&acc)[8][4])
{
    const int tid  = threadIdx.x;
    const int lane = tid & 63, w = tid >> 6;
    const int wr = w >> 2, wc = w & 3;
    const int lrow = lane & 15, kgrp = lane >> 4;
    const int srr = lane >> 2;          // staging row within 16-row group
    const int scc = (lane & 3) * 8;     // staging col (elems)

    auto stage = [&](int t, int isB, int kk) {
        const ushort* src = isB ? B : A;
        const int ld = isB ? ldb : lda;
        const int rb = isB ? bbase : abase;
        ushort* slot = (isB ? Bs : As) + (size_t)(((t & 1) * 2 + kk)) * 8192;
#pragma unroll
        for (int i = 0; i < 2; ++i) {
            const int r = (w * 2 + i) * 16 + srr;
            async16(&src[(size_t)(rb + r) * ld + t * 64 + kk * 32 + scc],
                    slot + (w * 2 + i) * 512);
        }
    };

#pragma unroll
    for (int m = 0; m < 8; ++m)
#pragma unroll
        for (int n = 0; n < 4; ++n) acc[m][n] = (f32x4){0.f, 0.f, 0.f, 0.f};

    // prologue: full K-tile 0, then k0-halves of K-tile 1
    stage(0, 0, 0); stage(0, 1, 0); stage(0, 0, 1); stage(0, 1, 1);
    if (NT > 1) {
        stage(1, 0, 0); stage(1, 1, 0);
        asm volatile("s_waitcnt vmcnt(4)" ::: "memory");   // K-tile 0 complete
    } else {
        asm volatile("s_waitcnt vmcnt(0)" ::: "memory");
    }
    SCHED();
    SBAR();
    SCHED();

    for (int t = 0; t < NT; ++t) {
        ushort* Ab = As + (size_t)(t & 1) * 2 * 8192;
        ushort* Bb = Bs + (size_t)(t & 1) * 2 * 8192;
        bf16x8 af[8], bfr[2];

        // ---- P1: quadrant (kk0, n0-1) ----
#pragma unroll
        for (int m = 0; m < 8; ++m)
            af[m] = *(const bf16x8*)&Ab[(wr * 128 + m * 16 + lrow) * 32 + kgrp * 8];
#pragma unroll
        for (int n = 0; n < 2; ++n)
            bfr[n] = *(const bf16x8*)&Bb[(wc * 64 + n * 16 + lrow) * 32 + kgrp * 8];
        if (t + 1 < NT) stage(t + 1, 0, 1);
        SBAR(); SCHED();
        __builtin_amdgcn_s_setprio(1);
#pragma unroll
        for (int m = 0; m < 8; ++m) {
            acc[m][0] = MFMA16(af[m], bfr[0], acc[m][0]);
            acc[m][1] = MFMA16(af[m], bfr[1], acc[m][1]);
        }
        __builtin_amdgcn_s_setprio(0);
        SBAR(); SCHED();

        // ---- P2: quadrant (kk0, n2-3) ----
#pragma unroll
        for (int n = 0; n < 2; ++n)
            bfr[n] = *(const bf16x8*)&Bb[(wc * 64 + (2 + n) * 16 + lrow) * 32 + kgrp * 8];
        if (t + 1 < NT) stage(t + 1, 1, 1);
        SBAR(); SCHED();
        __builtin_amdgcn_s_setprio(1);
#pragma unroll
        for (int m = 0; m < 8; ++m) {
            acc[m][2] = MFMA16(af[m], bfr[0], acc[m][2]);
            acc[m][3] = MFMA16(af[m], bfr[1], acc[m][3]);
        }
        __builtin_amdgcn_s_setprio(0);
        SBAR(); SCHED();

        // ---- P3: quadrant (kk1, n0-1) ----
#pragma unroll
        for (int m = 0; m < 8; ++m)
            af[m] = *(const bf16x8*)&Ab[8192 + (wr * 128 + m * 16 + lrow) * 32 + kgrp * 8];
#pragma unroll
        for (int n = 0; n < 2; ++n)
            bfr[n] = *(const bf16x8*)&Bb[8192 + (wc * 64 + n * 16 + lrow) * 32 + kgrp * 8];
        if (t + 2 < NT) stage(t + 2, 0, 0);
        SBAR(); SCHED();
        __builtin_amdgcn_s_setprio(1);
#pragma unroll
        for (int m = 0; m < 8; ++m) {
            acc[m][0] = MFMA16(af[m], bfr[0], acc[m][0]);
            acc[m][1] = MFMA16(af[m], bfr[1], acc[m][1]);
        }
        __builtin_amdgcn_s_setprio(0);
        SBAR(); SCHED();

        // ---- P4: quadrant (kk1, n2-3) ----
#pragma unroll
        for (int n = 0; n < 2; ++n)
            bfr[n] = *(const bf16x8*)&Bb[8192 + (wc * 64 + (2 + n) * 16 + lrow) * 32 + kgrp * 8];
        if (t + 2 < NT) {
            stage(t + 2, 1, 0);
            asm volatile("s_waitcnt vmcnt(4)" ::: "memory");  // t+1 fully staged
        } else if (t + 1 < NT) {
            asm volatile("s_waitcnt vmcnt(0)" ::: "memory");  // drain tail stages
        }
        SCHED();
        SBAR(); SCHED();
        __builtin_amdgcn_s_setprio(1);
#pragma unroll
        for (int m = 0; m < 8; ++m) {
            acc[m][2] = MFMA16(af[m], bfr[0], acc[m][2]);
            acc[m][3] = MFMA16(af[m], bfr[1], acc[m][3]);
        }
        __builtin_amdgcn_s_setprio(0);
        SBAR(); SCHED();
    }
}

// ---------------------------------------------------------------------------
// Kernel 1: Mtr[f][d] = (sum_e Wkt[f][e] * Wqt[d][e]) / 32  (scale folded).
// ---------------------------------------------------------------------------
__global__ __launch_bounds__(256) void m_gemm(
    const ushort* __restrict__ Wkt, const ushort* __restrict__ Wqt,
    ushort* __restrict__ Mtr)
{
    __shared__ ushort As[128 * 64];
    __shared__ ushort Bs[128 * 64];
    const int fbase = blockIdx.x * 128;
    const int dbase = blockIdx.y * 128;

    f32x4 acc[4][4];
    mma_tile(Wkt, 1024, fbase, Wqt, 1024, dbase, 16, As, Bs, acc);

    const int lane = threadIdx.x & 63, wid = threadIdx.x >> 6;
    const int wr = wid >> 1, wc = wid & 1;
    const int lrow = lane & 15, kgrp = lane >> 4;
#pragma unroll
    for (int m = 0; m < 4; ++m)
#pragma unroll
        for (int n = 0; n < 4; ++n)
#pragma unroll
            for (int r = 0; r < 4; ++r) {
                const int gf = fbase + wr * 64 + m * 16 + kgrp * 4 + r;
                const int gd = dbase + wc * 64 + n * 16 + lrow;
                Mtr[(size_t)gf * 1024 + gd] = f2bf(acc[m][n][r] * 0.03125f);
            }
}

// ---------------------------------------------------------------------------
// Kernel 2: 8-phase. z=0: T = xb @ Mtr^T -> Tb row-major. z=1: V -> Vt transposed.
// grid (32, 4, 2) = 256 blocks (1 per CU), 512 threads.
// ---------------------------------------------------------------------------
__global__ __launch_bounds__(512, 2) void tv_gemm8(
    const ushort* __restrict__ xb, const ushort* __restrict__ Mtr,
    const ushort* __restrict__ Wvb,
    ushort* __restrict__ Tb, ushort* __restrict__ Vt)
{
    __shared__ ushort As[2 * 2 * 8192];
    __shared__ ushort Bs[2 * 2 * 8192];

    const int z = blockIdx.z;
    const ushort* Bmat = z ? Wvb : Mtr;
    const int mbase = blockIdx.x * 256;
    const int nbase = blockIdx.y * 256;

    f32x4 acc[8][4];
    mma256(xb, 1024, mbase, Bmat, 1024, nbase, 16, As, Bs, acc);

    const int lane = threadIdx.x & 63, w = threadIdx.x >> 6;
    const int wr = w >> 2, wc = w & 3;
    const int lrow = lane & 15, kgrp = lane >> 4;

    if (z == 1) {
        // V transposed: Vt[batch][d][s], 4 consecutive s per 8B store
        const int b  = mbase >> 11;
        const int s0 = mbase & 2047;
        ushort* VtB = Vt + (size_t)b * 1024 * 2048;
#pragma unroll
        for (int m = 0; m < 8; ++m)
#pragma unroll
            for (int n = 0; n < 4; ++n) {
                u16x4 pk;
#pragma unroll
                for (int r = 0; r < 4; ++r) pk[r] = f2bf(acc[m][n][r]);
                const int d = nbase + wc * 64 + n * 16 + lrow;
                const int s = s0 + wr * 128 + m * 16 + kgrp * 4;
                *(u16x4*)&VtB[(size_t)d * 2048 + s] = pk;
            }
    } else {
#pragma unroll
        for (int m = 0; m < 8; ++m)
#pragma unroll
            for (int n = 0; n < 4; ++n)
#pragma unroll
                for (int r = 0; r < 4; ++r) {
                    const int gr = mbase + wr * 128 + m * 16 + kgrp * 4 + r;
                    const int gc = nbase + wc * 64 + n * 16 + lrow;
                    Tb[(size_t)gr * 1024 + gc] = f2bf(acc[m][n][r]);
                }
    }
}

// ---------------------------------------------------------------------------
// Kernel 3: 8-phase scores S = T @ x^T (scale already in T), lower-tri 256-tiles.
// grid (36, 4), 512 threads.
// ---------------------------------------------------------------------------
__global__ __launch_bounds__(512, 2) void scores_gemm8(
    const ushort* __restrict__ Tb, const ushort* __restrict__ xb,
    ushort* __restrict__ Sall)
{
    __shared__ ushort As[2 * 2 * 8192];
    __shared__ ushort Bs[2 * 2 * 8192];

    ushort* S = Sall + (size_t)blockIdx.y * 2048 * 2048;
    const int rb = blockIdx.y * 2048;

    int t = blockIdx.x;
    int it = (int)((sqrtf(8.0f * (float)t + 1.0f) - 1.0f) * 0.5f);
    while ((it + 1) * (it + 2) / 2 <= t) ++it;
    while (it * (it + 1) / 2 > t) --it;
    const int jt = t - it * (it + 1) / 2;
    const int ibase = it * 256, jbase = jt * 256;

    f32x4 acc[8][4];
    mma256(Tb, 1024, rb + ibase, xb, 1024, rb + jbase, 16, As, Bs, acc);

    const int lane = threadIdx.x & 63, w = threadIdx.x >> 6;
    const int wr = w >> 2, wc = w & 3;
    const int lrow = lane & 15, kgrp = lane >> 4;
#pragma unroll
    for (int m = 0; m < 8; ++m)
#pragma unroll
        for (int n = 0; n < 4; ++n)
#pragma unroll
            for (int r = 0; r < 4; ++r) {
                const int gi = ibase + wr * 128 + m * 16 + kgrp * 4 + r;
                const int gj = jbase + wc * 64 + n * 16 + lrow;
                S[(size_t)gi * 2048 + gj] = f2bf(acc[m][n][r]);
            }
}

// ---------------------------------------------------------------------------
// Kernel 4: causal row softmax in place on bf16 S. One block per row.
// Stores zeros above the diagonal (incl. tiles scores never wrote).
// ---------------------------------------------------------------------------
__global__ __launch_bounds__(256) void softmax_rows(ushort* __restrict__ Sall)
{
    ushort* S = Sall + (size_t)blockIdx.y * 2048 * 2048;
    const int i   = blockIdx.x;
    const int tid = threadIdx.x;
    const int j0  = tid * 8;

    union { uint4 v; ushort u[8]; } pk;
    const bool anyvalid = (j0 <= i);
    if (anyvalid) pk.v = *(const uint4*)&S[(size_t)i * 2048 + j0];

    float f[8];
    float mx = -INFINITY;
#pragma unroll
    for (int e = 0; e < 8; ++e) {
        float v = (anyvalid && (j0 + e <= i)) ? bf2f(pk.u[e]) : -INFINITY;
        f[e] = v;
        mx = fmaxf(mx, v);
    }
#pragma unroll
    for (int off = 1; off < 64; off <<= 1) mx = fmaxf(mx, __shfl_xor(mx, off));
    __shared__ float redm[4];
    if ((tid & 63) == 0) redm[tid >> 6] = mx;
    __syncthreads();
    mx = fmaxf(fmaxf(redm[0], redm[1]), fmaxf(redm[2], redm[3]));

    float s = 0.f;
#pragma unroll
    for (int e = 0; e < 8; ++e) {
        float p = __expf(f[e] - mx);
        f[e] = p;
        s += p;
    }
#pragma unroll
    for (int off = 1; off < 64; off <<= 1) s += __shfl_xor(s, off);
    __shared__ float reds[4];
    if ((tid & 63) == 0) reds[tid >> 6] = s;
    __syncthreads();
    s = reds[0] + reds[1] + reds[2] + reds[3];

    const float inv = 1.0f / s;
#pragma unroll
    for (int e = 0; e < 8; ++e) pk.u[e] = f2bf(f[e] * inv);
    *(uint4*)&S[(size_t)i * 2048 + j0] = pk.v;
}

// ---------------------------------------------------------------------------
// Kernel 5: O = P @ V (2-phase 128x128, K truncated at diagonal). fp32 out.
// ---------------------------------------------------------------------------
__global__ __launch_bounds__(256) void pv_gemm(
    const ushort* __restrict__ Pall, const ushort* __restrict__ Vtall,
    float* __restrict__ Oall)
{
    __shared__ ushort As[128 * 64];
    __shared__ ushort Bs[128 * 64];

    const ushort* P  = Pall  + (size_t)blockIdx.z * 2048 * 2048;
    const ushort* Vt = Vtall + (size_t)blockIdx.z * 1024 * 2048;
    float*        O  = Oall  + (size_t)blockIdx.z * 2048 * 1024;

    const int it = 15 - blockIdx.x;
    const int ibase = it * 128;
    const int nbase = blockIdx.y * 128;
    const int ktiles = 2 * (it + 1);

    f32x4 acc[4][4];
    mma_tile(P, 2048, ibase, Vt, 2048, nbase, ktiles, As, Bs, acc);

    const int lane = threadIdx.x & 63, wid = threadIdx.x >> 6;
    const int wr = wid >> 1, wc = wid & 1;
    const int lrow = lane & 15, kgrp = lane >> 4;
#pragma unroll
    for (int m = 0; m < 4; ++m)
#pragma unroll
        for (int n = 0; n < 4; ++n)
#pragma unroll
            for (int r = 0; r < 4; ++r) {
                const int gi = ibase + wr * 64 + m * 16 + kgrp * 4 + r;
                const int gc = nbase + wc * 64 + n * 16 + lrow;
                O[(size_t)gi * 1024 + gc] = acc[m][n][r];
            }
}

// ---------------------------------------------------------------------------
extern "C" void kernel_launch(void* const* d_in, const int* in_sizes, int n_in,
                              void* d_out, int out_size, void* d_ws, size_t ws_size,
                              hipStream_t stream)
{
    (void)in_sizes; (void)n_in; (void)out_size; (void)ws_size;
    const float* x  = (const float*)d_in[0];
    const float* Wk = (const float*)d_in[1];
    const float* Wq = (const float*)d_in[2];
    const float* Wv = (const float*)d_in[3];
    float* out = (float*)d_out;

    const size_t M1 = (size_t)1024 * 1024;
    ushort* ws  = (ushort*)d_ws;
    ushort* xb  = ws;                      // 8M elems
    ushort* Tb  = xb  + 8 * M1;            // 8M
    ushort* Vt  = Tb  + 8 * M1;            // 8M (4 x [1024][2048])
    ushort* Sb  = Vt  + 8 * M1;            // 16M (4 x [2048][2048])
    ushort* Wkt = Sb  + 16 * M1;           // 1M
    ushort* Wqt = Wkt + M1;                // 1M
    ushort* Wvb = Wqt + M1;                // 1M
    ushort* Mtr = Wvb + M1;                // 1M

    // 0b) transpose-convert Wk, Wq
    cvt_transpose<<<dim3(32, 32, 2), dim3(32, 8), 0, stream>>>(Wk, Wq, Wkt, Wqt);
    // 0a) straight-convert x, Wv
    cvt_bf16<<<4608, 256, 0, stream>>>(x, Wv, xb, Wvb);
    // 1) M = (Wq^T Wk)/32 stored transposed
    m_gemm<<<dim3(8, 8), 256, 0, stream>>>(Wkt, Wqt, Mtr);
    // 2) T = x@M (z=0), V^T (z=1); 256 blocks = 1/CU
    tv_gemm8<<<dim3(32, 4, 2), 512, 0, stream>>>(xb, Mtr, Wvb, Tb, Vt);
    // 3) scores, lower-triangular 256-tiles
    scores_gemm8<<<dim3(36, 4), 512, 0, stream>>>(Tb, xb, Sb);
    // 4) softmax in place
    softmax_rows<<<dim3(2048, 4), 256, 0, stream>>>(Sb);
    // 5) O = P @ V
    pv_gemm<<<dim3(16, 8, 4), 256, 0, stream>>>(Sb, Vt, out);
}